// Round 7
// baseline (482.609 us; speedup 1.0000x reference)
//
#include <hip/hip_runtime.h>
#include <hip/hip_bf16.h>
#include <cstdint>
#include <cstddef>

// Problem constants (B=8, S=2048, EMB=768, H=4, Dh=192)
#define EMB   768
#define HEADS 4
#define HD    192
#define BATCH 8
#define SEQ   2048
#define MROWS (BATCH * SEQ)   // 16384

typedef __attribute__((ext_vector_type(8))) short bf16x8;   // 8 bf16 = 4 VGPRs (MFMA A/B frag)
typedef __attribute__((ext_vector_type(4))) float f32x4;    // MFMA C/D frag

#define GLOBAL_AS __attribute__((address_space(1)))
#define LDS_AS    __attribute__((address_space(3)))

__device__ __forceinline__ void async16(unsigned short* lds, const unsigned short* g) {
    // 16B per lane, LDS dest = wave-uniform base + lane*16
    __builtin_amdgcn_global_load_lds((const GLOBAL_AS void*)g, (LDS_AS void*)lds, 16, 0, 0);
}

__device__ __forceinline__ unsigned short f2bf(float f) {
    union { float f; unsigned int u; } v; v.f = f;
    unsigned int u = v.u;
    unsigned int r = u + 0x7fffu + ((u >> 16) & 1u);  // RNE
    return (unsigned short)(r >> 16);
}

__device__ __forceinline__ unsigned long long pack4bf(float4 f) {
    union { __hip_bfloat162 h; unsigned int u; } a, b;
    a.h = __float22bfloat162_rn(make_float2(f.x, f.y));   // v_cvt_pk_bf16_f32
    b.h = __float22bfloat162_rn(make_float2(f.z, f.w));
    return (unsigned long long)a.u | ((unsigned long long)b.u << 32);
}

__device__ __forceinline__ int4 pack8bf(float4 lo, float4 hi) {
    union { unsigned long long u[2]; int4 i; } r;
    r.u[0] = pack4bf(lo);
    r.u[1] = pack4bf(hi);
    return r.i;
}

// XOR-swizzle: spread 16B blocks of a row across banks (CDNA attn recipe).
// XOR touches byte-addr bits [6:4] only. Verified conflict-free + correct in
// rounds 2-6 (SQ_LDS_BANK_CONFLICT = 0).
__device__ __forceinline__ int swz(int colbyte, int row) {
    return colbyte ^ ((row & 7) << 4);
}

// ---------------------------------------------------------------------------
// Elementwise fp32 -> bf16 convert, 16B loads / 8B stores (Wo only now).
// ---------------------------------------------------------------------------
__global__ __launch_bounds__(256) void conv_kernel(
    const float* __restrict__ x, unsigned short* __restrict__ y, int n4)
{
    int i = blockIdx.x * 256 + threadIdx.x;
    int stride = gridDim.x * 256;
    for (; i < n4; i += stride) {
        float4 f = ((const float4*)x)[i];
        ((unsigned long long*)y)[i] = pack4bf(f);
    }
}

// Three-tensor variant (Wq,Wk,Wv -> one slab).
__global__ __launch_bounds__(256) void conv3_kernel(
    const float* __restrict__ a, const float* __restrict__ b,
    const float* __restrict__ c, unsigned short* __restrict__ y, int n4)
{
    int i = blockIdx.x * 256 + threadIdx.x;
    int stride = gridDim.x * 256;
    for (; i < 3 * n4; i += stride) {
        int sel = i / n4, off = i - sel * n4;
        const float* s = (sel == 0) ? a : (sel == 1) ? b : c;
        float4 f = ((const float4*)s)[off];
        ((unsigned long long*)y)[i] = pack4bf(f);
    }
}

// ---------------------------------------------------------------------------
// bf16-A GEMM core (oproj): 128x128 tile, BK=32, double-buffered DMA.
// XCD-aware 1-D decode over 768 blocks (768%8==0, bijective).
// ---------------------------------------------------------------------------
#define GEMM_PROLOG                                                          \
    const int tid  = threadIdx.x;                                            \
    const int wg   = (blockIdx.x & 7) * 96 + (blockIdx.x >> 3);              \
    const int n0   = (wg % 6) * 128;                                         \
    const int m0   = (wg / 6) * 128;                                         \
    const int w    = tid >> 6;                                               \
    const int lane = tid & 63;                                               \
    const int l15  = lane & 15;                                              \
    const int quad = lane >> 4;                                              \
    const int wm   = (w >> 1) * 64;                                          \
    const int wn   = (w & 1) * 64;                                           \
    const int arow = lane >> 2;          /* row within 16-row async group */ \
    const int acol = (lane & 3) * 8;     /* 8-short col group */             \
    f32x4 acc[4][4];                                                         \
    _Pragma("unroll")                                                        \
    for (int a = 0; a < 4; a++)                                              \
        _Pragma("unroll")                                                    \
        for (int b = 0; b < 4; b++) acc[a][b] = (f32x4)0.0f;

#define GEMM_STAGE(buf, Aptr, Bptr, k0)                                      \
    _Pragma("unroll")                                                        \
    for (int j = 0; j < 2; j++) {                                            \
        int r = w * 32 + j * 16 + arow;                                      \
        async16(&Al[(buf) * 4096 + (w * 2 + j) * 512],                       \
                Aptr + (size_t)(m0 + r) * 768 + (k0) + acol);                \
        async16(&Bl[(buf) * 4096 + (w * 2 + j) * 512],                       \
                Bptr + (size_t)(n0 + r) * 768 + (k0) + acol);                \
    }

#define GEMM_COMPUTE(buf)                                                    \
    {                                                                        \
        bf16x8 af[4], bfr[4];                                                \
        _Pragma("unroll")                                                    \
        for (int mi = 0; mi < 4; mi++)                                       \
            af[mi] = *(const bf16x8*)&Al[(buf) * 4096 +                      \
                                         (wm + mi * 16 + l15) * 32 + quad * 8]; \
        _Pragma("unroll")                                                    \
        for (int ni = 0; ni < 4; ni++)                                       \
            bfr[ni] = *(const bf16x8*)&Bl[(buf) * 4096 +                     \
                                          (wn + ni * 16 + l15) * 32 + quad * 8]; \
        _Pragma("unroll")                                                    \
        for (int mi = 0; mi < 4; mi++)                                       \
            _Pragma("unroll")                                                \
            for (int ni = 0; ni < 4; ni++)                                   \
                acc[mi][ni] = __builtin_amdgcn_mfma_f32_16x16x32_bf16(       \
                    af[mi], bfr[ni], acc[mi][ni], 0, 0, 0);                  \
    }

#define GEMM_KLOOP(Aptr, Bptr)                                               \
    GEMM_STAGE(0, Aptr, Bptr, 0)                                             \
    for (int k0 = 0; k0 < 768; k0 += 64) {                                   \
        __syncthreads();                                                     \
        GEMM_STAGE(1, Aptr, Bptr, k0 + 32)                                   \
        GEMM_COMPUTE(0)                                                      \
        __syncthreads();                                                     \
        if (k0 + 64 < 768) { GEMM_STAGE(0, Aptr, Bptr, k0 + 64) }            \
        GEMM_COMPUTE(1)                                                      \
    }

// ---------------------------------------------------------------------------
// Fused Q/K/V projection, f32 input (conv fused into A-staging).
// Grid 2304 = 8 XCD x 3 proj x 96 tiles; each XCD sweeps its 96 tiles of Q,
// then K, then V -> one X stream + W L2-resident per XCD at any time.
// A-side: f32 loads issued at phase start, cvt_pk+ds_write after the MFMA
// block (issue-early/write-late); B-side (W bf16) via DMA. Double-buffered.
// sel==2 (V) uses the LDS-transpose epilogue -> Vb [B,H,HD,SEQ].
// ---------------------------------------------------------------------------
#define PROJ_A_LOAD(k0)                                                      \
    {                                                                        \
        const float* pa = X + (size_t)(m0 + w * 32 + arow) * 768 + (k0) + acol; \
        a0 = *(const float4*)pa;  a1 = *(const float4*)(pa + 4);             \
        a2 = *(const float4*)(pa + 16 * 768);                                \
        a3 = *(const float4*)(pa + 16 * 768 + 4);                            \
    }

#define PROJ_A_WRITE(buf)                                                    \
    {                                                                        \
        *(int4*)&Al[(buf) * 4096 + (w * 2 + 0) * 512 + lane * 8] = pack8bf(a0, a1); \
        *(int4*)&Al[(buf) * 4096 + (w * 2 + 1) * 512 + lane * 8] = pack8bf(a2, a3); \
    }

#define PROJ_B_STAGE(buf, k0)                                                \
    _Pragma("unroll")                                                        \
    for (int j = 0; j < 2; j++) {                                            \
        int r = w * 32 + j * 16 + arow;                                      \
        async16(&Bl[(buf) * 4096 + (w * 2 + j) * 512],                       \
                Wb + (size_t)(n0 + r) * 768 + (k0) + acol);                  \
    }

__global__ __launch_bounds__(256) void projqkv_kernel(
    const float* __restrict__ Xq, const float* __restrict__ Xk,
    const float* __restrict__ Xv,
    const unsigned short* __restrict__ Wall,   // [3][768*768] bf16
    const float* __restrict__ bqp, const float* __restrict__ bkp,
    const float* __restrict__ bvp,
    unsigned short* __restrict__ Qo, unsigned short* __restrict__ Ko,
    unsigned short* __restrict__ Vo)
{
    __shared__ __align__(16) unsigned short smem[16384];   // 2 x (A,B) = 32 KB
    unsigned short* Al = smem;          // [2][4096]
    unsigned short* Bl = smem + 8192;   // [2][4096]

    const int tid  = threadIdx.x;
    const int flat = blockIdx.x;          // 0..2303
    const int xcd  = flat & 7;
    const int loc  = flat >> 3;           // 0..287
    const int sel  = loc / 96;            // 0=Q, 1=K, 2=V
    const int wg   = xcd * 96 + (loc - sel * 96);   // 0..767
    const int n0   = (wg % 6) * 128;
    const int m0   = (wg / 6) * 128;
    const int w    = tid >> 6;
    const int lane = tid & 63;
    const int l15  = lane & 15;
    const int quad = lane >> 4;
    const int wm   = (w >> 1) * 64;
    const int wn   = (w & 1) * 64;
    const int arow = lane >> 2;
    const int acol = (lane & 3) * 8;

    const float* X = (sel == 0) ? Xq : (sel == 1) ? Xk : Xv;
    const unsigned short* Wb = Wall + (size_t)sel * (EMB * EMB);
    const float* bias = (sel == 0) ? bqp : (sel == 1) ? bkp : bvp;
    const float scale = (sel == 0) ? 0.07216878364870323f : 1.0f;

    f32x4 acc[4][4];
#pragma unroll
    for (int a = 0; a < 4; a++)
#pragma unroll
        for (int b = 0; b < 4; b++) acc[a][b] = (f32x4)0.0f;

    float4 a0, a1, a2, a3;

    // prologue: stage tile 0 into buf0
    PROJ_A_LOAD(0)
    PROJ_B_STAGE(0, 0)
    PROJ_A_WRITE(0)

    for (int k0 = 0; k0 < 768; k0 += 64) {
        __syncthreads();                 // buf0 (A writes + B DMA) visible
        PROJ_A_LOAD(k0 + 32)             // issue f32 loads early
        PROJ_B_STAGE(1, k0 + 32)         // issue W DMA early
        GEMM_COMPUTE(0)
        PROJ_A_WRITE(1)                  // cvt + ds_write late (WAR-safe)
        __syncthreads();                 // buf1 visible
        bool more = (k0 + 64) < 768;
        if (more) { PROJ_A_LOAD(k0 + 64) PROJ_B_STAGE(0, k0 + 64) }
        GEMM_COMPUTE(1)
        if (more) { PROJ_A_WRITE(0) }
    }

    if (sel < 2) {
        // ---- Q/K epilogue: [B,H,S,HD] bf16, scaled
        unsigned short* out = (sel == 0) ? Qo : Ko;
        const int b = m0 >> 11;   // tiles never straddle batches
#pragma unroll
        for (int mi = 0; mi < 4; mi++) {
#pragma unroll
            for (int ni = 0; ni < 4; ni++) {
                int jj = n0 + wn + ni * 16 + l15;
                int h  = jj / HD;
                int d  = jj - h * HD;
                float bj = bias[jj];
#pragma unroll
                for (int r = 0; r < 4; r++) {
                    int i = m0 + wm + mi * 16 + quad * 4 + r;
                    int s = i & (SEQ - 1);
                    out[(size_t)((b * HEADS + h) * SEQ + s) * HD + d] =
                        f2bf((acc[mi][ni][r] + bj) * scale);
                }
            }
        }
    } else {
        // ---- V epilogue: transpose to [B,H,HD,SEQ] via LDS
        __syncthreads();                // done with Al/Bl frag reads
        unsigned short* Tl = smem;      // 32 x 136 shorts
        const int batch = m0 >> 11;
        const int s0    = m0 & (SEQ - 1);
#pragma unroll
        for (int g = 0; g < 4; g++) {
            if ((w & 1) == (g >> 1)) {
#pragma unroll
                for (int t = 0; t < 2; t++) {
                    int ni = (g & 1) * 2 + t;
                    int jj = n0 + (w & 1) * 64 + ni * 16 + l15;
                    int dl = t * 16 + l15;
                    float bj = bias[jj];
#pragma unroll
                    for (int mi = 0; mi < 4; mi++)
#pragma unroll
                        for (int r = 0; r < 4; r++)
                            Tl[dl * 136 + wm + mi * 16 + quad * 4 + r] =
                                f2bf(acc[mi][ni][r] + bj);
                }
            }
            __syncthreads();
#pragma unroll
            for (int t = 0; t < 2; t++) {
                int u  = tid + t * 256;
                int dl = u >> 4;
                int cg = u & 15;
                int jj = n0 + g * 32 + dl;
                int hh = jj / HD;
                int d  = jj - hh * HD;
                *(int4*)(Vo + ((size_t)((batch * HEADS + hh) * HD + d)) * SEQ + s0 + cg * 8) =
                    *(const int4*)&Tl[dl * 136 + cg * 8];
            }
            __syncthreads();
        }
    }
}

// ---------------------------------------------------------------------------
// Output projection: out[m,j] = A[m,:].Wo[j,:] + bo[j], f32 out.
// ---------------------------------------------------------------------------
__global__ __launch_bounds__(256) void oproj_kernel(
    const unsigned short* __restrict__ A,   // [16384,768] bf16 (Ob)
    const unsigned short* __restrict__ Wb,  // [768,768] bf16
    const float* __restrict__ bias,
    float* __restrict__ out)                // [16384,768] f32
{
    __shared__ __align__(16) unsigned short smem[16384];
    unsigned short* Al = smem;          // [2][4096]
    unsigned short* Bl = smem + 8192;   // [2][4096]
    GEMM_PROLOG
    GEMM_KLOOP(A, Wb)

#pragma unroll
    for (int mi = 0; mi < 4; mi++) {
#pragma unroll
        for (int ni = 0; ni < 4; ni++) {
            int jj = n0 + wn + ni * 16 + l15;
            float bj = bias[jj];
#pragma unroll
            for (int r = 0; r < 4; r++) {
                int i = m0 + wm + mi * 16 + quad * 4 + r;
                out[(size_t)i * 768 + jj] = acc[mi][ni][r] + bj;
            }
        }
    }
}

// ---------------------------------------------------------------------------
// Flash attention v5 (unchanged since round 5: 161 us, MfmaUtil 27,
// conflicts 0, FETCH 41 MB): DMA staging with pre-swizzled source + linear
// LDS dest; 2 barriers/iter; full-phase load cover; setprio on MFMA.
// ---------------------------------------------------------------------------
__global__ __launch_bounds__(256, 2) void attn_kernel(
    const unsigned short* __restrict__ Q,
    const unsigned short* __restrict__ K,
    const unsigned short* __restrict__ Vt,
    unsigned short* __restrict__ O)     // [B,S,EMB] bf16
{
    __shared__ __align__(16) unsigned short Kl[64 * 192];    // 24 KB, swizzled
    __shared__ __align__(16) unsigned short Vl[192 * 64];    // 24 KB, swizzled
    __shared__ __align__(16) unsigned short Pl[4 * 32 * 64]; // 16 KB, swizzled

    const int tid  = threadIdx.x;
    const int w    = tid >> 6;
    const int lane = tid & 63;
    const int l15  = lane & 15;
    const int quad = lane >> 4;
    // XCD-aware decode: flat%8 = XCD -> each XCD exclusively owns 4 bh groups.
    const int flat = blockIdx.x;          // 0..511
    const int loc  = flat >> 3;           // 0..63 within XCD
    const int bh   = (flat & 7) * 4 + (loc >> 4);
    const int qt   = loc & 15;
    const int b    = bh >> 2;
    const int h    = bh & 3;
    const size_t kbase = (size_t)bh * SEQ * HD;

    // ---- Q fragments straight from global (one-time): 12 x 16B per lane
    bf16x8 qf[2][6];
    {
        const unsigned short* qp =
            Q + kbase + (size_t)(qt * 128 + w * 32 + l15) * HD + quad * 8;
#pragma unroll
        for (int mg = 0; mg < 2; mg++)
#pragma unroll
            for (int kk = 0; kk < 6; kk++)
                qf[mg][kk] = *(const bf16x8*)(qp + mg * 16 * HD + kk * 32);
    }

    // ---- prologue: DMA-stage K(0) -> Kl (pre-swizzled source, linear dest)
#pragma unroll
    for (int i = 0; i < 6; i++) {
        int u = tid + i * 256;
        int row = u / 24, rem = u - row * 24;
        int cgp = rem ^ (row & 7);       // inverse-swizzled source column
        async16(&Kl[(i * 256 + w * 64) * 8],
                K + kbase + (size_t)row * HD + cgp * 8);
    }

    f32x4 oacc[2][12];
#pragma unroll
    for (int mg = 0; mg < 2; mg++)
#pragma unroll
        for (int i = 0; i < 12; i++) oacc[mg][i] = (f32x4)0.0f;
    float lacc[2][4] = {{0.f, 0.f, 0.f, 0.f}, {0.f, 0.f, 0.f, 0.f}};

    for (int kt = 0; kt < SEQ / 64; kt++) {
        __syncthreads();                 // Kl(kt) visible; Vl free

        // ---- phase A: issue V(kt) DMA immediately (full phase of cover)
#pragma unroll
        for (int i = 0; i < 6; i++) {
            int u = tid + i * 256;
            int row = u >> 3;
            int cgp = (u & 7) ^ (row & 7);
            async16(&Vl[(i * 256 + w * 64) * 8],
                    Vt + kbase + (size_t)row * SEQ + kt * 64 + cgp * 8);
        }

        // QK^T: 48 MFMAs, 8 independent accumulation chains
        f32x4 sacc[2][4];
#pragma unroll
        for (int mg = 0; mg < 2; mg++)
#pragma unroll
            for (int nj = 0; nj < 4; nj++) sacc[mg][nj] = (f32x4)0.0f;

        __builtin_amdgcn_s_setprio(1);
#pragma unroll
        for (int kk = 0; kk < 6; kk++) {
#pragma unroll
            for (int nj = 0; nj < 4; nj++) {
                int row = nj * 16 + l15;
                bf16x8 bfr = *(const bf16x8*)((const char*)Kl + row * 384 +
                                              swz(kk * 64 + quad * 16, row));
                sacc[0][nj] = __builtin_amdgcn_mfma_f32_16x16x32_bf16(
                    qf[0][kk], bfr, sacc[0][nj], 0, 0, 0);
                sacc[1][nj] = __builtin_amdgcn_mfma_f32_16x16x32_bf16(
                    qf[1][kk], bfr, sacc[1][nj], 0, 0, 0);
            }
        }
        __builtin_amdgcn_s_setprio(0);

        // exp + deferred row sums; P -> wave-private swizzled LDS
        {
            char* pw = (char*)Pl + w * 4096;
#pragma unroll
            for (int mg = 0; mg < 2; mg++)
#pragma unroll
                for (int nj = 0; nj < 4; nj++) {
                    int colb = (nj * 16 + l15) * 2;
#pragma unroll
                    for (int r = 0; r < 4; r++) {
                        float pv = __expf(sacc[mg][nj][r]);
                        lacc[mg][r] += pv;
                        int row = mg * 16 + quad * 4 + r;
                        *(unsigned short*)(pw + row * 128 + swz(colb, row)) = f2bf(pv);
                    }
                }
        }

        __syncthreads();                 // Vl(kt)+Pl visible; Kl free

        // ---- phase B: issue K(kt+1) DMA immediately (full phase of cover)
        {
            int ktn = (kt + 1) & (SEQ / 64 - 1);   // last iter wraps (harmless)
#pragma unroll
            for (int i = 0; i < 6; i++) {
                int u = tid + i * 256;
                int row = u / 24, rem = u - row * 24;
                int cgp = rem ^ (row & 7);
                async16(&Kl[(i * 256 + w * 64) * 8],
                        K + kbase + (size_t)(ktn * 64 + row) * HD + cgp * 8);
            }
        }

        // PV: 48 MFMAs
#pragma unroll
        for (int kk = 0; kk < 2; kk++) {
            const char* pr = (const char*)Pl + w * 4096;
            bf16x8 pa0 = *(const bf16x8*)(pr + l15 * 128 + swz(kk * 64 + quad * 16, l15));
            bf16x8 pa1 = *(const bf16x8*)(pr + (16 + l15) * 128 + swz(kk * 64 + quad * 16, 16 + l15));
            __builtin_amdgcn_s_setprio(1);
#pragma unroll
            for (int nf = 0; nf < 12; nf++) {
                int vrow = nf * 16 + l15;
                bf16x8 vb = *(const bf16x8*)((const char*)Vl + vrow * 128 +
                                             swz(kk * 64 + quad * 16, vrow));
                oacc[0][nf] = __builtin_amdgcn_mfma_f32_16x16x32_bf16(pa0, vb, oacc[0][nf], 0, 0, 0);
                oacc[1][nf] = __builtin_amdgcn_mfma_f32_16x16x32_bf16(pa1, vb, oacc[1][nf], 0, 0, 0);
            }
            __builtin_amdgcn_s_setprio(0);
        }
    }

    // ---- final row-sum reduce (once) + epilogue
    float inv[2][4];
#pragma unroll
    for (int mg = 0; mg < 2; mg++)
#pragma unroll
        for (int r = 0; r < 4; r++) {
            float lsum = lacc[mg][r];
#pragma unroll
            for (int off = 1; off < 16; off <<= 1)
                lsum += __shfl_xor(lsum, off, 64);
            inv[mg][r] = 1.0f / lsum;
        }
#pragma unroll
    for (int mg = 0; mg < 2; mg++)
#pragma unroll
        for (int nf = 0; nf < 12; nf++) {
            int col = h * HD + nf * 16 + l15;
#pragma unroll
            for (int r = 0; r < 4; r++) {
                int s = qt * 128 + w * 32 + mg * 16 + quad * 4 + r;
                O[(size_t)(b * SEQ + s) * EMB + col] = f2bf(oacc[mg][nf][r] * inv[mg][r]);
            }
        }
}

// ---------------------------------------------------------------------------
extern "C" void kernel_launch(void* const* d_in, const int* in_sizes, int n_in,
                              void* d_out, int out_size, void* d_ws, size_t ws_size,
                              hipStream_t stream)
{
    const float* q  = (const float*)d_in[0];
    const float* k  = (const float*)d_in[1];
    const float* v  = (const float*)d_in[2];
    const float* Wq = (const float*)d_in[3];
    const float* bq = (const float*)d_in[4];
    const float* Wk = (const float*)d_in[5];
    const float* bk = (const float*)d_in[6];
    const float* Wv = (const float*)d_in[7];
    const float* bv = (const float*)d_in[8];
    const float* Wo = (const float*)d_in[9];
    const float* bo = (const float*)d_in[10];
    float* out = (float*)d_out;

    // Memory plan (d_ws = 100.66 MB). No Xbf scratch any more (projqkv reads
    // f32 inputs directly):
    //   d_ws: [S | Qb | Kb | Vb], 25.17 MB each.
    //     S: [Wq|Wk|Wv] bf16 (3.5 MB) during projqkv; Ob after attn.
    //     Qb: Q-proj result; after attn, reused for Wo-bf16.
    unsigned short* S   = (unsigned short*)d_ws;
    unsigned short* Qb  = S  + (size_t)MROWS * EMB;
    unsigned short* Kb  = Qb + (size_t)MROWS * EMB;
    unsigned short* Vb  = Kb + (size_t)MROWS * EMB;

    const int nw4 = EMB * EMB / 4;     // float4 count, W tensors
    dim3 pb(256);

    // 5-launch pipeline:
    conv3_kernel<<<dim3(1728), pb, 0, stream>>>(Wq, Wk, Wv, S, nw4);
    projqkv_kernel<<<dim3(2304), pb, 0, stream>>>(q, k, v, S, bq, bk, bv,
                                                  Qb, Kb, Vb);
    attn_kernel<<<dim3(512), pb, 0, stream>>>(Qb, Kb, Vb, S);   // S -> Ob
    conv_kernel<<<dim3(576), pb, 0, stream>>>(Wo, Qb, nw4);     // Qb -> Wo bf16
    oproj_kernel<<<dim3(768), pb, 0, stream>>>(S, Qb, bo, out);
}

// Round 8
// 451.971 us; speedup vs baseline: 1.0678x; 1.0678x over previous
//
#include <hip/hip_runtime.h>
#include <hip/hip_bf16.h>
#include <cstdint>
#include <cstddef>

// Problem constants (B=8, S=2048, EMB=768, H=4, Dh=192)
#define EMB   768
#define HEADS 4
#define HD    192
#define BATCH 8
#define SEQ   2048
#define MROWS (BATCH * SEQ)   // 16384

typedef __attribute__((ext_vector_type(8))) short bf16x8;   // 8 bf16 = 4 VGPRs (MFMA A/B frag)
typedef __attribute__((ext_vector_type(4))) float f32x4;    // MFMA C/D frag

#define GLOBAL_AS __attribute__((address_space(1)))
#define LDS_AS    __attribute__((address_space(3)))

__device__ __forceinline__ void async16(unsigned short* lds, const unsigned short* g) {
    // 16B per lane, LDS dest = wave-uniform base + lane*16
    __builtin_amdgcn_global_load_lds((const GLOBAL_AS void*)g, (LDS_AS void*)lds, 16, 0, 0);
}

__device__ __forceinline__ unsigned short f2bf(float f) {
    union { float f; unsigned int u; } v; v.f = f;
    unsigned int u = v.u;
    unsigned int r = u + 0x7fffu + ((u >> 16) & 1u);  // RNE
    return (unsigned short)(r >> 16);
}

__device__ __forceinline__ unsigned long long pack4bf(float4 f) {
    union { __hip_bfloat162 h; unsigned int u; } a, b;
    a.h = __float22bfloat162_rn(make_float2(f.x, f.y));   // v_cvt_pk_bf16_f32
    b.h = __float22bfloat162_rn(make_float2(f.z, f.w));
    return (unsigned long long)a.u | ((unsigned long long)b.u << 32);
}

__device__ __forceinline__ int4 pack8bf(float4 lo, float4 hi) {
    union { unsigned long long u[2]; int4 i; } r;
    r.u[0] = pack4bf(lo);
    r.u[1] = pack4bf(hi);
    return r.i;
}

// XOR-swizzle: spread 16B blocks of a row across banks. XOR touches byte-addr
// bits [6:4] only. Measured ZERO SQ_LDS_BANK_CONFLICT in attn (rounds 3-7)
// for both the 128B-row ds_write pattern and the 16-row frag-read pattern.
__device__ __forceinline__ int swz(int colbyte, int row) {
    return colbyte ^ ((row & 7) << 4);
}

// ---------------------------------------------------------------------------
// Elementwise fp32 -> bf16 convert (Wo only).
// ---------------------------------------------------------------------------
__global__ __launch_bounds__(256) void conv_kernel(
    const float* __restrict__ x, unsigned short* __restrict__ y, int n4)
{
    int i = blockIdx.x * 256 + threadIdx.x;
    int stride = gridDim.x * 256;
    for (; i < n4; i += stride) {
        float4 f = ((const float4*)x)[i];
        ((unsigned long long*)y)[i] = pack4bf(f);
    }
}

// Three-tensor variant (Wq,Wk,Wv -> one slab).
__global__ __launch_bounds__(256) void conv3_kernel(
    const float* __restrict__ a, const float* __restrict__ b,
    const float* __restrict__ c, unsigned short* __restrict__ y, int n4)
{
    int i = blockIdx.x * 256 + threadIdx.x;
    int stride = gridDim.x * 256;
    for (; i < 3 * n4; i += stride) {
        int sel = i / n4, off = i - sel * n4;
        const float* s = (sel == 0) ? a : (sel == 1) ? b : c;
        float4 f = ((const float4*)s)[off];
        ((unsigned long long*)y)[i] = pack4bf(f);
    }
}

// ---------------------------------------------------------------------------
// GEMM core v3: 128x128 tile, BK=64, LDS [128][64] shorts (128B rows, bank-
// aligned) with XOR-swizzle -> conflict-free frag reads (attn-proven layout).
// Double-buffered: 12 K-tiles as 6 double-steps; staging for tile t+1 issued
// at the top of tile t's compute -> full-tile (~1200cy) latency cover.
// DMA staging: linear LDS dest + pre-swizzled source column (involution).
// LDS 64 KB -> 2 blocks/CU. XCD-aware 1-D decode over 768 blocks.
// ---------------------------------------------------------------------------
#define GEMM_PROLOG                                                          \
    const int tid  = threadIdx.x;                                            \
    const int wg   = (blockIdx.x & 7) * 96 + (blockIdx.x >> 3);              \
    const int n0   = (wg % 6) * 128;                                         \
    const int m0   = (wg / 6) * 128;                                         \
    const int w    = tid >> 6;                                               \
    const int lane = tid & 63;                                               \
    const int l15  = lane & 15;                                              \
    const int quad = lane >> 4;                                              \
    const int wm   = (w >> 1) * 64;                                          \
    const int wn   = (w & 1) * 64;                                           \
    const int aw8  = w * 8;              /* staging row base within round */ \
    const int ar8  = lane >> 3;          /* staging row offset (0..7) */     \
    const int acg  = lane & 7;           /* staging 16B col slot (0..7) */   \
    f32x4 acc[4][4];                                                         \
    _Pragma("unroll")                                                        \
    for (int a = 0; a < 4; a++)                                              \
        _Pragma("unroll")                                                    \
        for (int b = 0; b < 4; b++) acc[a][b] = (f32x4)0.0f;

// DMA one 128x64 tile into buf (4 rounds x 256 threads x 16B = 16 KB).
// LDS image: [row][slot] where slot s holds source col-slot s ^ (row&7).
#define STAGE_DMA(dst, buf, Sptr, base, k0)                                  \
    _Pragma("unroll")                                                        \
    for (int i = 0; i < 4; i++) {                                            \
        int row = i * 32 + aw8 + ar8;                                        \
        int cgp = acg ^ (row & 7);                                           \
        async16(&dst[(buf) * 8192 + (i * 256 + w * 64) * 8],                 \
                Sptr + (size_t)(base + row) * 768 + (k0) + cgp * 8);         \
    }

#define GEMM_COMPUTE_V3(buf)                                                 \
    _Pragma("unroll")                                                        \
    for (int kk = 0; kk < 2; kk++) {                                         \
        bf16x8 af[4], bfr[4];                                                \
        _Pragma("unroll")                                                    \
        for (int mi = 0; mi < 4; mi++) {                                     \
            int row = wm + mi * 16 + l15;                                    \
            af[mi] = *(const bf16x8*)((const char*)Al + (buf) * 16384 +      \
                         row * 128 + swz(kk * 64 + quad * 16, row));         \
        }                                                                    \
        _Pragma("unroll")                                                    \
        for (int ni = 0; ni < 4; ni++) {                                     \
            int row = wn + ni * 16 + l15;                                    \
            bfr[ni] = *(const bf16x8*)((const char*)Bl + (buf) * 16384 +     \
                          row * 128 + swz(kk * 64 + quad * 16, row));        \
        }                                                                    \
        _Pragma("unroll")                                                    \
        for (int mi = 0; mi < 4; mi++)                                       \
            _Pragma("unroll")                                                \
            for (int ni = 0; ni < 4; ni++)                                   \
                acc[mi][ni] = __builtin_amdgcn_mfma_f32_16x16x32_bf16(       \
                    af[mi], bfr[ni], acc[mi][ni], 0, 0, 0);                  \
    }

#define GEMM_KLOOP_V3(Aptr, Bptr)                                            \
    STAGE_DMA(Al, 0, Aptr, m0, 0)                                            \
    STAGE_DMA(Bl, 0, Bptr, n0, 0)                                            \
    for (int k0 = 0; k0 < 768; k0 += 128) {                                  \
        __syncthreads();                                                     \
        STAGE_DMA(Al, 1, Aptr, m0, k0 + 64)                                  \
        STAGE_DMA(Bl, 1, Bptr, n0, k0 + 64)                                  \
        GEMM_COMPUTE_V3(0)                                                   \
        __syncthreads();                                                     \
        if (k0 + 128 < 768) {                                                \
            STAGE_DMA(Al, 0, Aptr, m0, k0 + 128)                             \
            STAGE_DMA(Bl, 0, Bptr, n0, k0 + 128)                             \
        }                                                                    \
        GEMM_COMPUTE_V3(1)                                                   \
    }

// ---------------------------------------------------------------------------
// Fused Q/K/V projection, f32 input. Grid 2304 = 8 XCD x {3 proj x 96 tiles}.
// A-side: 8 f32x4 loads issued at phase start (issue-early), pack to bf16 +
// swizzled ds_write after the MFMA block (write-late; write pattern = attn Vl,
// measured 0 conflicts). B-side (W bf16): DMA. Double-buffered BK=64.
// ---------------------------------------------------------------------------
#define PROJQKV_A_LOAD(k0)                                                   \
    _Pragma("unroll")                                                        \
    for (int i = 0; i < 4; i++) {                                            \
        int row = i * 32 + aw8 + ar8;                                        \
        const float* pa = X + (size_t)(m0 + row) * 768 + (k0) + acg * 8;     \
        av[2 * i]     = *(const float4*)pa;                                  \
        av[2 * i + 1] = *(const float4*)(pa + 4);                            \
    }

#define PROJQKV_A_WRITE(buf)                                                 \
    _Pragma("unroll")                                                        \
    for (int i = 0; i < 4; i++) {                                            \
        int row = i * 32 + aw8 + ar8;                                        \
        *(int4*)((char*)Al + (buf) * 16384 + row * 128 + swz(acg * 16, row)) \
            = pack8bf(av[2 * i], av[2 * i + 1]);                             \
    }

__global__ __launch_bounds__(256) void projqkv_kernel(
    const float* __restrict__ Xq, const float* __restrict__ Xk,
    const float* __restrict__ Xv,
    const unsigned short* __restrict__ Wall,   // [3][768*768] bf16
    const float* __restrict__ bqp, const float* __restrict__ bkp,
    const float* __restrict__ bvp,
    unsigned short* __restrict__ Qo, unsigned short* __restrict__ Ko,
    unsigned short* __restrict__ Vo)
{
    __shared__ __align__(16) unsigned short smem[32768];   // 64 KB
    unsigned short* Al = smem;           // [2][128][64]
    unsigned short* Bl = smem + 16384;   // [2][128][64]

    const int tid  = threadIdx.x;
    const int flat = blockIdx.x;          // 0..2303
    const int xcd  = flat & 7;
    const int loc  = flat >> 3;           // 0..287
    const int sel  = loc / 96;            // 0=Q, 1=K, 2=V
    const int wg   = xcd * 96 + (loc - sel * 96);   // 0..767
    const int n0   = (wg % 6) * 128;
    const int m0   = (wg / 6) * 128;
    const int w    = tid >> 6;
    const int lane = tid & 63;
    const int l15  = lane & 15;
    const int quad = lane >> 4;
    const int wm   = (w >> 1) * 64;
    const int wn   = (w & 1) * 64;
    const int aw8  = w * 8;
    const int ar8  = lane >> 3;
    const int acg  = lane & 7;

    const float* X = (sel == 0) ? Xq : (sel == 1) ? Xk : Xv;
    const unsigned short* Wb = Wall + (size_t)sel * (EMB * EMB);
    const float* bias = (sel == 0) ? bqp : (sel == 1) ? bkp : bvp;
    const float scale = (sel == 0) ? 0.07216878364870323f : 1.0f;

    f32x4 acc[4][4];
#pragma unroll
    for (int a = 0; a < 4; a++)
#pragma unroll
        for (int b = 0; b < 4; b++) acc[a][b] = (f32x4)0.0f;

    float4 av[8];

    // prologue: tile 0 into buf0
    PROJQKV_A_LOAD(0)
    STAGE_DMA(Bl, 0, Wb, n0, 0)
    PROJQKV_A_WRITE(0)

    for (int k0 = 0; k0 < 768; k0 += 128) {
        __syncthreads();                 // buf0 visible (A writes + B DMA)
        PROJQKV_A_LOAD(k0 + 64)          // issue f32 loads early
        STAGE_DMA(Bl, 1, Wb, n0, k0 + 64)
        GEMM_COMPUTE_V3(0)
        PROJQKV_A_WRITE(1)               // cvt + swizzled ds_write late
        __syncthreads();                 // buf1 visible
        bool more = (k0 + 128) < 768;
        if (more) {
            PROJQKV_A_LOAD(k0 + 128)
            STAGE_DMA(Bl, 0, Wb, n0, k0 + 128)
        }
        GEMM_COMPUTE_V3(1)
        if (more) { PROJQKV_A_WRITE(0) }
    }

    if (sel < 2) {
        // ---- Q/K epilogue: [B,H,S,HD] bf16, scaled
        unsigned short* out = (sel == 0) ? Qo : Ko;
        const int b = m0 >> 11;   // tiles never straddle batches
#pragma unroll
        for (int mi = 0; mi < 4; mi++) {
#pragma unroll
            for (int ni = 0; ni < 4; ni++) {
                int jj = n0 + wn + ni * 16 + l15;
                int h  = jj / HD;
                int d  = jj - h * HD;
                float bj = bias[jj];
#pragma unroll
                for (int r = 0; r < 4; r++) {
                    int i = m0 + wm + mi * 16 + quad * 4 + r;
                    int s = i & (SEQ - 1);
                    out[(size_t)((b * HEADS + h) * SEQ + s) * HD + d] =
                        f2bf((acc[mi][ni][r] + bj) * scale);
                }
            }
        }
    } else {
        // ---- V epilogue: transpose to [B,H,HD,SEQ] via LDS
        __syncthreads();                // done with Al/Bl frag reads
        unsigned short* Tl = smem;      // 32 x 136 shorts
        const int batch = m0 >> 11;
        const int s0    = m0 & (SEQ - 1);
#pragma unroll
        for (int g = 0; g < 4; g++) {
            if ((w & 1) == (g >> 1)) {
#pragma unroll
                for (int t = 0; t < 2; t++) {
                    int ni = (g & 1) * 2 + t;
                    int jj = n0 + (w & 1) * 64 + ni * 16 + l15;
                    int dl = t * 16 + l15;
                    float bj = bias[jj];
#pragma unroll
                    for (int mi = 0; mi < 4; mi++)
#pragma unroll
                        for (int r = 0; r < 4; r++)
                            Tl[dl * 136 + wm + mi * 16 + quad * 4 + r] =
                                f2bf(acc[mi][ni][r] + bj);
                }
            }
            __syncthreads();
#pragma unroll
            for (int t = 0; t < 2; t++) {
                int u  = tid + t * 256;
                int dl = u >> 4;
                int cg = u & 15;
                int jj = n0 + g * 32 + dl;
                int hh = jj / HD;
                int d  = jj - hh * HD;
                *(int4*)(Vo + ((size_t)((batch * HEADS + hh) * HD + d)) * SEQ + s0 + cg * 8) =
                    *(const int4*)&Tl[dl * 136 + cg * 8];
            }
            __syncthreads();
        }
    }
}

// ---------------------------------------------------------------------------
// Output projection: out[m,j] = A[m,:].Wo[j,:] + bo[j], f32 out. v3 core.
// ---------------------------------------------------------------------------
__global__ __launch_bounds__(256) void oproj_kernel(
    const unsigned short* __restrict__ A,   // [16384,768] bf16 (Ob)
    const unsigned short* __restrict__ Wb,  // [768,768] bf16
    const float* __restrict__ bias,
    float* __restrict__ out)                // [16384,768] f32
{
    __shared__ __align__(16) unsigned short smem[32768];
    unsigned short* Al = smem;           // [2][128][64]
    unsigned short* Bl = smem + 16384;   // [2][128][64]
    GEMM_PROLOG
    GEMM_KLOOP_V3(A, Wb)

#pragma unroll
    for (int mi = 0; mi < 4; mi++) {
#pragma unroll
        for (int ni = 0; ni < 4; ni++) {
            int jj = n0 + wn + ni * 16 + l15;
            float bj = bias[jj];
#pragma unroll
            for (int r = 0; r < 4; r++) {
                int i = m0 + wm + mi * 16 + quad * 4 + r;
                out[(size_t)i * 768 + jj] = acc[mi][ni][r] + bj;
            }
        }
    }
}

// ---------------------------------------------------------------------------
// Flash attention v5 (unchanged since round 5: 161 us, MfmaUtil 27,
// conflicts 0, FETCH 41 MB): DMA staging with pre-swizzled source + linear
// LDS dest; 2 barriers/iter; full-phase load cover; setprio on MFMA.
// ---------------------------------------------------------------------------
__global__ __launch_bounds__(256, 2) void attn_kernel(
    const unsigned short* __restrict__ Q,
    const unsigned short* __restrict__ K,
    const unsigned short* __restrict__ Vt,
    unsigned short* __restrict__ O)     // [B,S,EMB] bf16
{
    __shared__ __align__(16) unsigned short Kl[64 * 192];    // 24 KB, swizzled
    __shared__ __align__(16) unsigned short Vl[192 * 64];    // 24 KB, swizzled
    __shared__ __align__(16) unsigned short Pl[4 * 32 * 64]; // 16 KB, swizzled

    const int tid  = threadIdx.x;
    const int w    = tid >> 6;
    const int lane = tid & 63;
    const int l15  = lane & 15;
    const int quad = lane >> 4;
    // XCD-aware decode: flat%8 = XCD -> each XCD exclusively owns 4 bh groups.
    const int flat = blockIdx.x;          // 0..511
    const int loc  = flat >> 3;           // 0..63 within XCD
    const int bh   = (flat & 7) * 4 + (loc >> 4);
    const int qt   = loc & 15;
    const int b    = bh >> 2;
    const int h    = bh & 3;
    const size_t kbase = (size_t)bh * SEQ * HD;

    // ---- Q fragments straight from global (one-time): 12 x 16B per lane
    bf16x8 qf[2][6];
    {
        const unsigned short* qp =
            Q + kbase + (size_t)(qt * 128 + w * 32 + l15) * HD + quad * 8;
#pragma unroll
        for (int mg = 0; mg < 2; mg++)
#pragma unroll
            for (int kk = 0; kk < 6; kk++)
                qf[mg][kk] = *(const bf16x8*)(qp + mg * 16 * HD + kk * 32);
    }

    // ---- prologue: DMA-stage K(0) -> Kl (pre-swizzled source, linear dest)
#pragma unroll
    for (int i = 0; i < 6; i++) {
        int u = tid + i * 256;
        int row = u / 24, rem = u - row * 24;
        int cgp = rem ^ (row & 7);       // inverse-swizzled source column
        async16(&Kl[(i * 256 + w * 64) * 8],
                K + kbase + (size_t)row * HD + cgp * 8);
    }

    f32x4 oacc[2][12];
#pragma unroll
    for (int mg = 0; mg < 2; mg++)
#pragma unroll
        for (int i = 0; i < 12; i++) oacc[mg][i] = (f32x4)0.0f;
    float lacc[2][4] = {{0.f, 0.f, 0.f, 0.f}, {0.f, 0.f, 0.f, 0.f}};

    for (int kt = 0; kt < SEQ / 64; kt++) {
        __syncthreads();                 // Kl(kt) visible; Vl free

        // ---- phase A: issue V(kt) DMA immediately (full phase of cover)
#pragma unroll
        for (int i = 0; i < 6; i++) {
            int u = tid + i * 256;
            int row = u >> 3;
            int cgp = (u & 7) ^ (row & 7);
            async16(&Vl[(i * 256 + w * 64) * 8],
                    Vt + kbase + (size_t)row * SEQ + kt * 64 + cgp * 8);
        }

        // QK^T: 48 MFMAs, 8 independent accumulation chains
        f32x4 sacc[2][4];
#pragma unroll
        for (int mg = 0; mg < 2; mg++)
#pragma unroll
            for (int nj = 0; nj < 4; nj++) sacc[mg][nj] = (f32x4)0.0f;

        __builtin_amdgcn_s_setprio(1);
#pragma unroll
        for (int kk = 0; kk < 6; kk++) {
#pragma unroll
            for (int nj = 0; nj < 4; nj++) {
                int row = nj * 16 + l15;
                bf16x8 bfr = *(const bf16x8*)((const char*)Kl + row * 384 +
                                              swz(kk * 64 + quad * 16, row));
                sacc[0][nj] = __builtin_amdgcn_mfma_f32_16x16x32_bf16(
                    qf[0][kk], bfr, sacc[0][nj], 0, 0, 0);
                sacc[1][nj] = __builtin_amdgcn_mfma_f32_16x16x32_bf16(
                    qf[1][kk], bfr, sacc[1][nj], 0, 0, 0);
            }
        }
        __builtin_amdgcn_s_setprio(0);

        // exp + deferred row sums; P -> wave-private swizzled LDS
        {
            char* pw = (char*)Pl + w * 4096;
#pragma unroll
            for (int mg = 0; mg < 2; mg++)
#pragma unroll
                for (int nj = 0; nj < 4; nj++) {
                    int colb = (nj * 16 + l15) * 2;
#pragma unroll
                    for (int r = 0; r < 4; r++) {
                        float pv = __expf(sacc[mg][nj][r]);
                        lacc[mg][r] += pv;
                        int row = mg * 16 + quad * 4 + r;
                        *(unsigned short*)(pw + row * 128 + swz(colb, row)) = f2bf(pv);
                    }
                }
        }

        __syncthreads();                 // Vl(kt)+Pl visible; Kl free

        // ---- phase B: issue K(kt+1) DMA immediately (full phase of cover)
        {
            int ktn = (kt + 1) & (SEQ / 64 - 1);   // last iter wraps (harmless)
#pragma unroll
            for (int i = 0; i < 6; i++) {
                int u = tid + i * 256;
                int row = u / 24, rem = u - row * 24;
                int cgp = rem ^ (row & 7);
                async16(&Kl[(i * 256 + w * 64) * 8],
                        K + kbase + (size_t)(ktn * 64 + row) * HD + cgp * 8);
            }
        }

        // PV: 48 MFMAs
#pragma unroll
        for (int kk = 0; kk < 2; kk++) {
            const char* pr = (const char*)Pl + w * 4096;
            bf16x8 pa0 = *(const bf16x8*)(pr + l15 * 128 + swz(kk * 64 + quad * 16, l15));
            bf16x8 pa1 = *(const bf16x8*)(pr + (16 + l15) * 128 + swz(kk * 64 + quad * 16, 16 + l15));
            __builtin_amdgcn_s_setprio(1);
#pragma unroll
            for (int nf = 0; nf < 12; nf++) {
                int vrow = nf * 16 + l15;
                bf16x8 vb = *(const bf16x8*)((const char*)Vl + vrow * 128 +
                                             swz(kk * 64 + quad * 16, vrow));
                oacc[0][nf] = __builtin_amdgcn_mfma_f32_16x16x32_bf16(pa0, vb, oacc[0][nf], 0, 0, 0);
                oacc[1][nf] = __builtin_amdgcn_mfma_f32_16x16x32_bf16(pa1, vb, oacc[1][nf], 0, 0, 0);
            }
            __builtin_amdgcn_s_setprio(0);
        }
    }

    // ---- final row-sum reduce (once) + epilogue
    float inv[2][4];
#pragma unroll
    for (int mg = 0; mg < 2; mg++)
#pragma unroll
        for (int r = 0; r < 4; r++) {
            float lsum = lacc[mg][r];
#pragma unroll
            for (int off = 1; off < 16; off <<= 1)
                lsum += __shfl_xor(lsum, off, 64);
            inv[mg][r] = 1.0f / lsum;
        }
#pragma unroll
    for (int mg = 0; mg < 2; mg++)
#pragma unroll
        for (int nf = 0; nf < 12; nf++) {
            int col = h * HD + nf * 16 + l15;
#pragma unroll
            for (int r = 0; r < 4; r++) {
                int s = qt * 128 + w * 32 + mg * 16 + quad * 4 + r;
                O[(size_t)(b * SEQ + s) * EMB + col] = f2bf(oacc[mg][nf][r] * inv[mg][r]);
            }
        }
}

// ---------------------------------------------------------------------------
extern "C" void kernel_launch(void* const* d_in, const int* in_sizes, int n_in,
                              void* d_out, int out_size, void* d_ws, size_t ws_size,
                              hipStream_t stream)
{
    const float* q  = (const float*)d_in[0];
    const float* k  = (const float*)d_in[1];
    const float* v  = (const float*)d_in[2];
    const float* Wq = (const float*)d_in[3];
    const float* bq = (const float*)d_in[4];
    const float* Wk = (const float*)d_in[5];
    const float* bk = (const float*)d_in[6];
    const float* Wv = (const float*)d_in[7];
    const float* bv = (const float*)d_in[8];
    const float* Wo = (const float*)d_in[9];
    const float* bo = (const float*)d_in[10];
    float* out = (float*)d_out;

    // Memory plan (d_ws = 100.66 MB):
    //   d_ws: [S | Qb | Kb | Vb], 25.17 MB each.
    //     S: [Wq|Wk|Wv] bf16 (3.5 MB) during projqkv; Ob after attn.
    //     Qb: Q-proj result; after attn, reused for Wo-bf16.
    unsigned short* S   = (unsigned short*)d_ws;
    unsigned short* Qb  = S  + (size_t)MROWS * EMB;
    unsigned short* Kb  = Qb + (size_t)MROWS * EMB;
    unsigned short* Vb  = Kb + (size_t)MROWS * EMB;

    const int nw4 = EMB * EMB / 4;     // float4 count, W tensors
    dim3 pb(256);

    // 5-launch pipeline:
    conv3_kernel<<<dim3(1728), pb, 0, stream>>>(Wq, Wk, Wv, S, nw4);
    projqkv_kernel<<<dim3(2304), pb, 0, stream>>>(q, k, v, S, bq, bk, bv,
                                                  Qb, Kb, Vb);
    attn_kernel<<<dim3(512), pb, 0, stream>>>(Qb, Kb, Vb, S);   // S -> Ob
    conv_kernel<<<dim3(576), pb, 0, stream>>>(Wo, Qb, nw4);     // Qb -> Wo bf16
    oproj_kernel<<<dim3(768), pb, 0, stream>>>(S, Qb, bo, out);
}

// Round 9
// 402.768 us; speedup vs baseline: 1.1982x; 1.1222x over previous
//
#include <hip/hip_runtime.h>
#include <hip/hip_bf16.h>
#include <cstdint>
#include <cstddef>

// Problem constants (B=8, S=2048, EMB=768, H=4, Dh=192)
#define EMB   768
#define HEADS 4
#define HD    192
#define BATCH 8
#define SEQ   2048
#define MROWS (BATCH * SEQ)   // 16384

typedef __attribute__((ext_vector_type(8))) short bf16x8;   // 8 bf16 = 4 VGPRs (MFMA A/B frag)
typedef __attribute__((ext_vector_type(4))) float f32x4;    // MFMA C/D frag

#define GLOBAL_AS __attribute__((address_space(1)))
#define LDS_AS    __attribute__((address_space(3)))

__device__ __forceinline__ void async16(unsigned short* lds, const unsigned short* g) {
    // 16B per lane, LDS dest = wave-uniform base + lane*16
    __builtin_amdgcn_global_load_lds((const GLOBAL_AS void*)g, (LDS_AS void*)lds, 16, 0, 0);
}

__device__ __forceinline__ unsigned short f2bf(float f) {
    union { float f; unsigned int u; } v; v.f = f;
    unsigned int u = v.u;
    unsigned int r = u + 0x7fffu + ((u >> 16) & 1u);  // RNE
    return (unsigned short)(r >> 16);
}

__device__ __forceinline__ unsigned long long pack4bf(float4 f) {
    union { __hip_bfloat162 h; unsigned int u; } a, b;
    a.h = __float22bfloat162_rn(make_float2(f.x, f.y));   // v_cvt_pk_bf16_f32
    b.h = __float22bfloat162_rn(make_float2(f.z, f.w));
    return (unsigned long long)a.u | ((unsigned long long)b.u << 32);
}

__device__ __forceinline__ int4 pack8bf(float4 lo, float4 hi) {
    union { unsigned long long u[2]; int4 i; } r;
    r.u[0] = pack4bf(lo);
    r.u[1] = pack4bf(hi);
    return r.i;
}

// XOR-swizzle: spread 16B blocks of a row across banks. XOR touches byte-addr
// bits [6:4] only. Measured ZERO SQ_LDS_BANK_CONFLICT in attn (rounds 3-8)
// for the 128B-row ds_write/frag-read patterns.
__device__ __forceinline__ int swz(int colbyte, int row) {
    return colbyte ^ ((row & 7) << 4);
}

// ---------------------------------------------------------------------------
// Elementwise fp32 -> bf16 convert (Wo only).
// ---------------------------------------------------------------------------
__global__ __launch_bounds__(256) void conv_kernel(
    const float* __restrict__ x, unsigned short* __restrict__ y, int n4)
{
    int i = blockIdx.x * 256 + threadIdx.x;
    int stride = gridDim.x * 256;
    for (; i < n4; i += stride) {
        float4 f = ((const float4*)x)[i];
        ((unsigned long long*)y)[i] = pack4bf(f);
    }
}

// Three-tensor variant (Wq,Wk,Wv -> one slab).
__global__ __launch_bounds__(256) void conv3_kernel(
    const float* __restrict__ a, const float* __restrict__ b,
    const float* __restrict__ c, unsigned short* __restrict__ y, int n4)
{
    int i = blockIdx.x * 256 + threadIdx.x;
    int stride = gridDim.x * 256;
    for (; i < 3 * n4; i += stride) {
        int sel = i / n4, off = i - sel * n4;
        const float* s = (sel == 0) ? a : (sel == 1) ? b : c;
        float4 f = ((const float4*)s)[off];
        ((unsigned long long*)y)[i] = pack4bf(f);
    }
}

// ---------------------------------------------------------------------------
// GEMM core v3 (unchanged from round 8): 128x128 tile, BK=64, LDS [128][64]
// shorts with XOR-swizzle (conflict-free), double-buffered DMA, XCD decode.
// ---------------------------------------------------------------------------
#define GEMM_PROLOG                                                          \
    const int tid  = threadIdx.x;                                            \
    const int wg   = (blockIdx.x & 7) * 96 + (blockIdx.x >> 3);              \
    const int n0   = (wg % 6) * 128;                                         \
    const int m0   = (wg / 6) * 128;                                         \
    const int w    = tid >> 6;                                               \
    const int lane = tid & 63;                                               \
    const int l15  = lane & 15;                                              \
    const int quad = lane >> 4;                                              \
    const int wm   = (w >> 1) * 64;                                          \
    const int wn   = (w & 1) * 64;                                           \
    const int aw8  = w * 8;              /* staging row base within round */ \
    const int ar8  = lane >> 3;          /* staging row offset (0..7) */     \
    const int acg  = lane & 7;           /* staging 16B col slot (0..7) */   \
    f32x4 acc[4][4];                                                         \
    _Pragma("unroll")                                                        \
    for (int a = 0; a < 4; a++)                                              \
        _Pragma("unroll")                                                    \
        for (int b = 0; b < 4; b++) acc[a][b] = (f32x4)0.0f;

#define STAGE_DMA(dst, buf, Sptr, base, k0)                                  \
    _Pragma("unroll")                                                        \
    for (int i = 0; i < 4; i++) {                                            \
        int row = i * 32 + aw8 + ar8;                                        \
        int cgp = acg ^ (row & 7);                                           \
        async16(&dst[(buf) * 8192 + (i * 256 + w * 64) * 8],                 \
                Sptr + (size_t)(base + row) * 768 + (k0) + cgp * 8);         \
    }

#define GEMM_COMPUTE_V3(buf)                                                 \
    _Pragma("unroll")                                                        \
    for (int kk = 0; kk < 2; kk++) {                                         \
        bf16x8 af[4], bfr[4];                                                \
        _Pragma("unroll")                                                    \
        for (int mi = 0; mi < 4; mi++) {                                     \
            int row = wm + mi * 16 + l15;                                    \
            af[mi] = *(const bf16x8*)((const char*)Al + (buf) * 16384 +      \
                         row * 128 + swz(kk * 64 + quad * 16, row));         \
        }                                                                    \
        _Pragma("unroll")                                                    \
        for (int ni = 0; ni < 4; ni++) {                                     \
            int row = wn + ni * 16 + l15;                                    \
            bfr[ni] = *(const bf16x8*)((const char*)Bl + (buf) * 16384 +     \
                          row * 128 + swz(kk * 64 + quad * 16, row));        \
        }                                                                    \
        _Pragma("unroll")                                                    \
        for (int mi = 0; mi < 4; mi++)                                       \
            _Pragma("unroll")                                                \
            for (int ni = 0; ni < 4; ni++)                                   \
                acc[mi][ni] = __builtin_amdgcn_mfma_f32_16x16x32_bf16(       \
                    af[mi], bfr[ni], acc[mi][ni], 0, 0, 0);                  \
    }

#define GEMM_KLOOP_V3(Aptr, Bptr)                                            \
    STAGE_DMA(Al, 0, Aptr, m0, 0)                                            \
    STAGE_DMA(Bl, 0, Bptr, n0, 0)                                            \
    for (int k0 = 0; k0 < 768; k0 += 128) {                                  \
        __syncthreads();                                                     \
        STAGE_DMA(Al, 1, Aptr, m0, k0 + 64)                                  \
        STAGE_DMA(Bl, 1, Bptr, n0, k0 + 64)                                  \
        GEMM_COMPUTE_V3(0)                                                   \
        __syncthreads();                                                     \
        if (k0 + 128 < 768) {                                                \
            STAGE_DMA(Al, 0, Aptr, m0, k0 + 128)                             \
            STAGE_DMA(Bl, 0, Bptr, n0, k0 + 128)                             \
        }                                                                    \
        GEMM_COMPUTE_V3(1)                                                   \
    }

// ---------------------------------------------------------------------------
// Fused Q/K/V projection, f32 input (unchanged from round 8).
// ---------------------------------------------------------------------------
#define PROJQKV_A_LOAD(k0)                                                   \
    _Pragma("unroll")                                                        \
    for (int i = 0; i < 4; i++) {                                            \
        int row = i * 32 + aw8 + ar8;                                        \
        const float* pa = X + (size_t)(m0 + row) * 768 + (k0) + acg * 8;     \
        av[2 * i]     = *(const float4*)pa;                                  \
        av[2 * i + 1] = *(const float4*)(pa + 4);                            \
    }

#define PROJQKV_A_WRITE(buf)                                                 \
    _Pragma("unroll")                                                        \
    for (int i = 0; i < 4; i++) {                                            \
        int row = i * 32 + aw8 + ar8;                                        \
        *(int4*)((char*)Al + (buf) * 16384 + row * 128 + swz(acg * 16, row)) \
            = pack8bf(av[2 * i], av[2 * i + 1]);                             \
    }

__global__ __launch_bounds__(256) void projqkv_kernel(
    const float* __restrict__ Xq, const float* __restrict__ Xk,
    const float* __restrict__ Xv,
    const unsigned short* __restrict__ Wall,   // [3][768*768] bf16
    const float* __restrict__ bqp, const float* __restrict__ bkp,
    const float* __restrict__ bvp,
    unsigned short* __restrict__ Qo, unsigned short* __restrict__ Ko,
    unsigned short* __restrict__ Vo)
{
    __shared__ __align__(16) unsigned short smem[32768];   // 64 KB
    unsigned short* Al = smem;           // [2][128][64]
    unsigned short* Bl = smem + 16384;   // [2][128][64]

    const int tid  = threadIdx.x;
    const int flat = blockIdx.x;          // 0..2303
    const int xcd  = flat & 7;
    const int loc  = flat >> 3;           // 0..287
    const int sel  = loc / 96;            // 0=Q, 1=K, 2=V
    const int wg   = xcd * 96 + (loc - sel * 96);   // 0..767
    const int n0   = (wg % 6) * 128;
    const int m0   = (wg / 6) * 128;
    const int w    = tid >> 6;
    const int lane = tid & 63;
    const int l15  = lane & 15;
    const int quad = lane >> 4;
    const int wm   = (w >> 1) * 64;
    const int wn   = (w & 1) * 64;
    const int aw8  = w * 8;
    const int ar8  = lane >> 3;
    const int acg  = lane & 7;

    const float* X = (sel == 0) ? Xq : (sel == 1) ? Xk : Xv;
    const unsigned short* Wb = Wall + (size_t)sel * (EMB * EMB);
    const float* bias = (sel == 0) ? bqp : (sel == 1) ? bkp : bvp;
    const float scale = (sel == 0) ? 0.07216878364870323f : 1.0f;

    f32x4 acc[4][4];
#pragma unroll
    for (int a = 0; a < 4; a++)
#pragma unroll
        for (int b = 0; b < 4; b++) acc[a][b] = (f32x4)0.0f;

    float4 av[8];

    // prologue: tile 0 into buf0
    PROJQKV_A_LOAD(0)
    STAGE_DMA(Bl, 0, Wb, n0, 0)
    PROJQKV_A_WRITE(0)

    for (int k0 = 0; k0 < 768; k0 += 128) {
        __syncthreads();                 // buf0 visible (A writes + B DMA)
        PROJQKV_A_LOAD(k0 + 64)          // issue f32 loads early
        STAGE_DMA(Bl, 1, Wb, n0, k0 + 64)
        GEMM_COMPUTE_V3(0)
        PROJQKV_A_WRITE(1)               // cvt + swizzled ds_write late
        __syncthreads();                 // buf1 visible
        bool more = (k0 + 128) < 768;
        if (more) {
            PROJQKV_A_LOAD(k0 + 128)
            STAGE_DMA(Bl, 0, Wb, n0, k0 + 128)
        }
        GEMM_COMPUTE_V3(1)
        if (more) { PROJQKV_A_WRITE(0) }
    }

    if (sel < 2) {
        // ---- Q/K epilogue: [B,H,S,HD] bf16, scaled
        unsigned short* out = (sel == 0) ? Qo : Ko;
        const int b = m0 >> 11;   // tiles never straddle batches
#pragma unroll
        for (int mi = 0; mi < 4; mi++) {
#pragma unroll
            for (int ni = 0; ni < 4; ni++) {
                int jj = n0 + wn + ni * 16 + l15;
                int h  = jj / HD;
                int d  = jj - h * HD;
                float bj = bias[jj];
#pragma unroll
                for (int r = 0; r < 4; r++) {
                    int i = m0 + wm + mi * 16 + quad * 4 + r;
                    int s = i & (SEQ - 1);
                    out[(size_t)((b * HEADS + h) * SEQ + s) * HD + d] =
                        f2bf((acc[mi][ni][r] + bj) * scale);
                }
            }
        }
    } else {
        // ---- V epilogue: transpose to [B,H,HD,SEQ] via LDS
        __syncthreads();                // done with Al/Bl frag reads
        unsigned short* Tl = smem;      // 32 x 136 shorts
        const int batch = m0 >> 11;
        const int s0    = m0 & (SEQ - 1);
#pragma unroll
        for (int g = 0; g < 4; g++) {
            if ((w & 1) == (g >> 1)) {
#pragma unroll
                for (int t = 0; t < 2; t++) {
                    int ni = (g & 1) * 2 + t;
                    int jj = n0 + (w & 1) * 64 + ni * 16 + l15;
                    int dl = t * 16 + l15;
                    float bj = bias[jj];
#pragma unroll
                    for (int mi = 0; mi < 4; mi++)
#pragma unroll
                        for (int r = 0; r < 4; r++)
                            Tl[dl * 136 + wm + mi * 16 + quad * 4 + r] =
                                f2bf(acc[mi][ni][r] + bj);
                }
            }
            __syncthreads();
#pragma unroll
            for (int t = 0; t < 2; t++) {
                int u  = tid + t * 256;
                int dl = u >> 4;
                int cg = u & 15;
                int jj = n0 + g * 32 + dl;
                int hh = jj / HD;
                int d  = jj - hh * HD;
                *(int4*)(Vo + ((size_t)((batch * HEADS + hh) * HD + d)) * SEQ + s0 + cg * 8) =
                    *(const int4*)&Tl[dl * 136 + cg * 8];
            }
            __syncthreads();
        }
    }
}

// ---------------------------------------------------------------------------
// Output projection: out[m,j] = A[m,:].Wo[j,:] + bo[j], f32 out. v3 core.
// ---------------------------------------------------------------------------
__global__ __launch_bounds__(256) void oproj_kernel(
    const unsigned short* __restrict__ A,   // [16384,768] bf16 (Ob)
    const unsigned short* __restrict__ Wb,  // [768,768] bf16
    const float* __restrict__ bias,
    float* __restrict__ out)                // [16384,768] f32
{
    __shared__ __align__(16) unsigned short smem[32768];
    unsigned short* Al = smem;           // [2][128][64]
    unsigned short* Bl = smem + 16384;   // [2][128][64]
    GEMM_PROLOG
    GEMM_KLOOP_V3(A, Wb)

#pragma unroll
    for (int mi = 0; mi < 4; mi++) {
#pragma unroll
        for (int ni = 0; ni < 4; ni++) {
            int jj = n0 + wn + ni * 16 + l15;
            float bj = bias[jj];
#pragma unroll
            for (int r = 0; r < 4; r++) {
                int i = m0 + wm + mi * 16 + quad * 4 + r;
                out[(size_t)i * 768 + jj] = acc[mi][ni][r] + bj;
            }
        }
    }
}

// ---------------------------------------------------------------------------
// Flash attention v6: swapped-QK vectorized-P.
// QK computes S^T = mfma(A=K_frag, B=Q_frag): thread (quad,l15) holds
// P[q = mg*16 + l15][k = njk*16 + quad*4 + r] -- 4 CONSECUTIVE k per
// (njk): exp -> cvt_pk pairs -> ONE ds_write_b64 (was 32 scalar b16 writes
// + 128 f2bf VALU ops). P LDS image is byte-identical to v5's ([32 q][64 k]
// row-major, 128B rows, swz'd; byte(k)=2k both sides) -> PV phase unchanged.
// Row-sum: thread owns one q-row -> reduce over quads (shfl_xor 16,32);
// inv gathered per C/D row via 8 lane-indexed shfl at the end.
// Rest identical to v5: DMA staging w/ pre-swizzled source, 2 barriers/iter,
// full-phase load cover, setprio, XCD decode. LDS 64 KB, 2 blocks/CU.
// ---------------------------------------------------------------------------
__global__ __launch_bounds__(256, 2) void attn_kernel(
    const unsigned short* __restrict__ Q,
    const unsigned short* __restrict__ K,
    const unsigned short* __restrict__ Vt,
    unsigned short* __restrict__ O)     // [B,S,EMB] bf16
{
    __shared__ __align__(16) unsigned short Kl[64 * 192];    // 24 KB, swizzled
    __shared__ __align__(16) unsigned short Vl[192 * 64];    // 24 KB, swizzled
    __shared__ __align__(16) unsigned short Pl[4 * 32 * 64]; // 16 KB, swizzled

    const int tid  = threadIdx.x;
    const int w    = tid >> 6;
    const int lane = tid & 63;
    const int l15  = lane & 15;
    const int quad = lane >> 4;
    // XCD-aware decode: flat%8 = XCD -> each XCD exclusively owns 4 bh groups.
    const int flat = blockIdx.x;          // 0..511
    const int loc  = flat >> 3;           // 0..63 within XCD
    const int bh   = (flat & 7) * 4 + (loc >> 4);
    const int qt   = loc & 15;
    const int b    = bh >> 2;
    const int h    = bh & 3;
    const size_t kbase = (size_t)bh * SEQ * HD;

    // ---- Q fragments straight from global (one-time): 12 x 16B per lane
    bf16x8 qf[2][6];
    {
        const unsigned short* qp =
            Q + kbase + (size_t)(qt * 128 + w * 32 + l15) * HD + quad * 8;
#pragma unroll
        for (int mg = 0; mg < 2; mg++)
#pragma unroll
            for (int kk = 0; kk < 6; kk++)
                qf[mg][kk] = *(const bf16x8*)(qp + mg * 16 * HD + kk * 32);
    }

    // ---- prologue: DMA-stage K(0) -> Kl (pre-swizzled source, linear dest)
#pragma unroll
    for (int i = 0; i < 6; i++) {
        int u = tid + i * 256;
        int row = u / 24, rem = u - row * 24;
        int cgp = rem ^ (row & 7);       // inverse-swizzled source column
        async16(&Kl[(i * 256 + w * 64) * 8],
                K + kbase + (size_t)row * HD + cgp * 8);
    }

    f32x4 oacc[2][12];
#pragma unroll
    for (int mg = 0; mg < 2; mg++)
#pragma unroll
        for (int i = 0; i < 12; i++) oacc[mg][i] = (f32x4)0.0f;
    float lacc[2] = {0.f, 0.f};          // per-thread: one q-row per mg

    for (int kt = 0; kt < SEQ / 64; kt++) {
        __syncthreads();                 // Kl(kt) visible; Vl free

        // ---- phase A: issue V(kt) DMA immediately (full phase of cover)
#pragma unroll
        for (int i = 0; i < 6; i++) {
            int u = tid + i * 256;
            int row = u >> 3;
            int cgp = (u & 7) ^ (row & 7);
            async16(&Vl[(i * 256 + w * 64) * 8],
                    Vt + kbase + (size_t)row * SEQ + kt * 64 + cgp * 8);
        }

        // QK^T swapped: sacc[mg][njk] = S^T block, 8 independent chains
        f32x4 sacc[2][4];
#pragma unroll
        for (int mg = 0; mg < 2; mg++)
#pragma unroll
            for (int njk = 0; njk < 4; njk++) sacc[mg][njk] = (f32x4)0.0f;

        __builtin_amdgcn_s_setprio(1);
#pragma unroll
        for (int kk = 0; kk < 6; kk++) {
#pragma unroll
            for (int njk = 0; njk < 4; njk++) {
                int row = njk * 16 + l15;
                bf16x8 kf = *(const bf16x8*)((const char*)Kl + row * 384 +
                                             swz(kk * 64 + quad * 16, row));
                // A = K-frag, B = Q-frag -> D[k][q]
                sacc[0][njk] = __builtin_amdgcn_mfma_f32_16x16x32_bf16(
                    kf, qf[0][kk], sacc[0][njk], 0, 0, 0);
                sacc[1][njk] = __builtin_amdgcn_mfma_f32_16x16x32_bf16(
                    kf, qf[1][kk], sacc[1][njk], 0, 0, 0);
            }
        }
        __builtin_amdgcn_s_setprio(0);

        // exp + row sums + vectorized P store: one b64 per (mg,njk)
        {
            char* pw = (char*)Pl + w * 4096;
#pragma unroll
            for (int mg = 0; mg < 2; mg++) {
                int row = mg * 16 + l15;         // q-row within wave tile
#pragma unroll
                for (int njk = 0; njk < 4; njk++) {
                    float e0 = __expf(sacc[mg][njk][0]);
                    float e1 = __expf(sacc[mg][njk][1]);
                    float e2 = __expf(sacc[mg][njk][2]);
                    float e3 = __expf(sacc[mg][njk][3]);
                    lacc[mg] += (e0 + e1) + (e2 + e3);
                    int colb = njk * 32 + quad * 8;   // byte(k) = 2k
                    *(unsigned long long*)(pw + row * 128 + swz(colb, row)) =
                        pack4bf(make_float4(e0, e1, e2, e3));
                }
            }
        }

        __syncthreads();                 // Vl(kt)+Pl visible; Kl free

        // ---- phase B: issue K(kt+1) DMA immediately (full phase of cover)
        {
            int ktn = (kt + 1) & (SEQ / 64 - 1);   // last iter wraps (harmless)
#pragma unroll
            for (int i = 0; i < 6; i++) {
                int u = tid + i * 256;
                int row = u / 24, rem = u - row * 24;
                int cgp = rem ^ (row & 7);
                async16(&Kl[(i * 256 + w * 64) * 8],
                        K + kbase + (size_t)(ktn * 64 + row) * HD + cgp * 8);
            }
        }

        // PV: 48 MFMAs (unchanged; P LDS image identical to v5)
#pragma unroll
        for (int kk = 0; kk < 2; kk++) {
            const char* pr = (const char*)Pl + w * 4096;
            bf16x8 pa0 = *(const bf16x8*)(pr + l15 * 128 + swz(kk * 64 + quad * 16, l15));
            bf16x8 pa1 = *(const bf16x8*)(pr + (16 + l15) * 128 + swz(kk * 64 + quad * 16, 16 + l15));
            __builtin_amdgcn_s_setprio(1);
#pragma unroll
            for (int nf = 0; nf < 12; nf++) {
                int vrow = nf * 16 + l15;
                bf16x8 vb = *(const bf16x8*)((const char*)Vl + vrow * 128 +
                                             swz(kk * 64 + quad * 16, vrow));
                oacc[0][nf] = __builtin_amdgcn_mfma_f32_16x16x32_bf16(pa0, vb, oacc[0][nf], 0, 0, 0);
                oacc[1][nf] = __builtin_amdgcn_mfma_f32_16x16x32_bf16(pa1, vb, oacc[1][nf], 0, 0, 0);
            }
            __builtin_amdgcn_s_setprio(0);
        }
    }

    // ---- final reduce: sum over quads (lanes ±16/±32 share a q-row)
    float inv[2][4];
#pragma unroll
    for (int mg = 0; mg < 2; mg++) {
        float ls = lacc[mg];
        ls += __shfl_xor(ls, 16, 64);
        ls += __shfl_xor(ls, 32, 64);
        // gather inv for C/D rows quad*4+r (held by lane l15=quad*4+r)
#pragma unroll
        for (int r = 0; r < 4; r++)
            inv[mg][r] = 1.0f / __shfl(ls, quad * 4 + r, 64);
    }
#pragma unroll
    for (int mg = 0; mg < 2; mg++)
#pragma unroll
        for (int nf = 0; nf < 12; nf++) {
            int col = h * HD + nf * 16 + l15;
#pragma unroll
            for (int r = 0; r < 4; r++) {
                int s = qt * 128 + w * 32 + mg * 16 + quad * 4 + r;
                O[(size_t)(b * SEQ + s) * EMB + col] = f2bf(oacc[mg][nf][r] * inv[mg][r]);
            }
        }
}

// ---------------------------------------------------------------------------
extern "C" void kernel_launch(void* const* d_in, const int* in_sizes, int n_in,
                              void* d_out, int out_size, void* d_ws, size_t ws_size,
                              hipStream_t stream)
{
    const float* q  = (const float*)d_in[0];
    const float* k  = (const float*)d_in[1];
    const float* v  = (const float*)d_in[2];
    const float* Wq = (const float*)d_in[3];
    const float* bq = (const float*)d_in[4];
    const float* Wk = (const float*)d_in[5];
    const float* bk = (const float*)d_in[6];
    const float* Wv = (const float*)d_in[7];
    const float* bv = (const float*)d_in[8];
    const float* Wo = (const float*)d_in[9];
    const float* bo = (const float*)d_in[10];
    float* out = (float*)d_out;

    // Memory plan (d_ws = 100.66 MB):
    //   d_ws: [S | Qb | Kb | Vb], 25.17 MB each.
    //     S: [Wq|Wk|Wv] bf16 (3.5 MB) during projqkv; Ob after attn.
    //     Qb: Q-proj result; after attn, reused for Wo-bf16.
    unsigned short* S   = (unsigned short*)d_ws;
    unsigned short* Qb  = S  + (size_t)MROWS * EMB;
    unsigned short* Kb  = Qb + (size_t)MROWS * EMB;
    unsigned short* Vb  = Kb + (size_t)MROWS * EMB;

    const int nw4 = EMB * EMB / 4;     // float4 count, W tensors
    dim3 pb(256);

    // 5-launch pipeline:
    conv3_kernel<<<dim3(1728), pb, 0, stream>>>(Wq, Wk, Wv, S, nw4);
    projqkv_kernel<<<dim3(2304), pb, 0, stream>>>(q, k, v, S, bq, bk, bv,
                                                  Qb, Kb, Vb);
    attn_kernel<<<dim3(512), pb, 0, stream>>>(Qb, Kb, Vb, S);   // S -> Ob
    conv_kernel<<<dim3(576), pb, 0, stream>>>(Wo, Qb, nw4);     // Qb -> Wo bf16
    oproj_kernel<<<dim3(768), pb, 0, stream>>>(S, Qb, bo, out);
}